// Round 10
// baseline (2642.016 us; speedup 1.0000x reference)
//
#include <hip/hip_runtime.h>

#define NP   19
#define EPB  16
#define BLK  256
#define WST  260        // s_W row stride (words)
#define RSTRIDE 4864    // P_TOTAL columns in R

__device__ __constant__ int   c_lf[NP]  = {0,1,2, 1,0,1,2,1,2,3, 2,1,2,3, 0,1,2,3,4};
__device__ __constant__ int   c_cgb[NP] = {0,1,10, 35,44,53,80,125,170,245, 350,375,420,495, 600,625,700,825,1000};
__device__ __constant__ float c_nrm[5]  = {1.0f, 0.57735026918962576f, 0.44721359549995794f,
                                           0.37796447300922722f, 0.33333333333333333f};

// ---- one (io,ii) class: dO/dI compile-time, loop over the class's paths ----
// ALL LDS exchanges are intra-wave (wave wv writes W/cgy/tmp only for edges
// 4wv..4wv+3, which are exactly the elocs of wave wv) -> no barriers, fences only.
template<int IO, int II, int PB, int PE>
__device__ __forceinline__ void do_class(
    const int l, const int eloc, const int wv, const int c4,
    const float (&rr)[40], const float (&fv)[9], float (&acc)[2*IO+1],
    const float* __restrict__ R,
    const float* __restrict__ s_cg, const float* __restrict__ s_y,
    float* __restrict__ s_cgy, float* __restrict__ s_tmp, float* __restrict__ s_W)
{
    constexpr int dO  = 2*IO + 1, dI = 2*II + 1;
    constexpr int nOI = dO * dI;
    constexpr int FO  = (II == 0) ? 0 : (II == 1) ? 1 : 4;

    #pragma unroll 1
    for (int p = PB; p < PE; ++p) {
        const int   lf  = c_lf[p];
        const int   dF  = 2*lf + 1;
        const int   yb  = lf*lf;
        const int   cgb = c_cgb[p];
        const float nrm = c_nrm[lf];

        // ---- W-gen: cols 4c4..4c4+3 of edges 4wv..4wv+3 (own wave's edges) ----
        float4 Wacc[4];
        #pragma unroll
        for (int ee = 0; ee < 4; ++ee) Wacc[ee] = float4{0.f,0.f,0.f,0.f};
        const float* Rp = R + p*256 + 4*c4;
        #pragma unroll
        for (int r = 0; r < 10; ++r) {
            const float4 q = *reinterpret_cast<const float4*>(Rp + r*RSTRIDE);
            #pragma unroll
            for (int ee = 0; ee < 4; ++ee) {
                const float rv = rr[ee*10 + r];
                Wacc[ee].x += rv*q.x; Wacc[ee].y += rv*q.y;
                Wacc[ee].z += rv*q.z; Wacc[ee].w += rv*q.w;
            }
        }
        #pragma unroll
        for (int ee = 0; ee < 4; ++ee)
            *reinterpret_cast<float4*>(&s_W[(4*wv + ee)*WST + 4*c4]) = Wacc[ee];

        // ---- cgY[o,i] = nrm * sum_f cg[.]*y[.]  (16 lanes of eloc cover nOI) ----
        #pragma unroll
        for (int j0 = 0; j0 < nOI; j0 += 16) {
            const int j = j0 + l;
            if (j < nOI) {
                float s = 0.f;
                const float* cgp = &s_cg[cgb + j*dF];
                const float* yp  = &s_y[eloc*26 + yb];
                for (int f = 0; f < dF; ++f) s += cgp[f] * yp[f];
                s_cgy[eloc*28 + j] = s * nrm;
            }
        }
        __asm__ volatile("" ::: "memory");   // cgY + W writes ordered before reads (same wave)

        // ---- tmp[v,o] = sum_i fv[FO+i] * cgY[o*dI+i]   (lane = v) ----
        #pragma unroll
        for (int o = 0; o < dO; ++o) {
            float t = 0.f;
            #pragma unroll
            for (int i = 0; i < dI; ++i) t += fv[FO + i] * s_cgy[eloc*28 + o*dI + i];
            s_tmp[eloc*84 + o*16 + l] = t;
        }
        __asm__ volatile("" ::: "memory");   // tmp writes ordered before stage-3 reads

        // ---- acc[o] += sum_v W[w=l, v] * tmp[v, o] ----
        {
            const float* Wr = &s_W[eloc*WST + 16*l];
            const float4 w0 = *reinterpret_cast<const float4*>(Wr);
            const float4 w1 = *reinterpret_cast<const float4*>(Wr + 4);
            const float4 w2 = *reinterpret_cast<const float4*>(Wr + 8);
            const float4 w3 = *reinterpret_cast<const float4*>(Wr + 12);
            #pragma unroll
            for (int o = 0; o < dO; ++o) {
                const float4* tq = reinterpret_cast<const float4*>(&s_tmp[eloc*84 + o*16]);
                const float4 t0 = tq[0], t1 = tq[1], t2 = tq[2], t3 = tq[3];
                acc[o] += w0.x*t0.x + w0.y*t0.y + w0.z*t0.z + w0.w*t0.w
                        + w1.x*t1.x + w1.y*t1.y + w1.z*t1.z + w1.w*t1.w
                        + w2.x*t2.x + w2.y*t2.y + w2.z*t2.z + w2.w*t2.w
                        + w3.x*t3.x + w3.y*t3.y + w3.z*t3.z + w3.w*t3.w;
            }
        }
        __asm__ volatile("" ::: "memory");   // WAR: next path rewrites s_W/s_cgy/s_tmp
    }
}

// ---------------- Phase A: edge-major messages, zero-barrier main loop ----------------
__global__ __launch_bounds__(BLK, 4)
void se3_msg(const float* __restrict__ F, const float* __restrict__ R,
             const float* __restrict__ Ys, const float* __restrict__ Rad,
             const float* __restrict__ cg,
             const int* __restrict__ Mb,
             float* __restrict__ msg, const int nE)
{
    __shared__ float s_cg [1225];
    __shared__ float s_y  [EPB*26];
    __shared__ float s_cgy[EPB*28];
    __shared__ float s_tmp[EPB*84];
    __shared__ float s_W  [EPB*WST];

    const int tid  = threadIdx.x;
    const int l    = tid & 15;
    const int eloc = tid >> 4;
    const int wv   = tid >> 6;
    const int c4   = tid & 63;
    const int e    = blockIdx.x * EPB + eloc;
    const bool act = (e < nE);
    const int  es  = act ? e : 0;

    for (int t = tid; t < 1225; t += BLK) s_cg[t] = cg[t];

    // radii for own wave's 4 edges -> registers (wave-uniform addresses)
    float rr[40];
    {
        const int e0 = blockIdx.x * EPB + 4*wv;
        #pragma unroll
        for (int ee = 0; ee < 4; ++ee) {
            const int  ge = e0 + ee;
            const bool a  = (ge < nE);
            const float* rp = Rad + (size_t)(a ? ge : 0) * 10;
            #pragma unroll
            for (int r = 0; r < 10; ++r) rr[ee*10 + r] = a ? rp[r] : 0.f;  // inactive -> W=0
        }
    }

    // Ys row for own edge -> LDS (runtime yb index later); intra-wave
    for (int k = l; k < 25; k += 16) s_y[eloc*26 + k] = Ys[(size_t)es*25 + k];

    // F slices for own (edge, lane) -> registers (compile-time indexed)
    float fv[9];
    {
        const int b = Mb[es];
        const float* Fb = F + (size_t)b * 144;
        fv[0] = Fb[l];
        #pragma unroll
        for (int i = 0; i < 3; ++i) fv[1 + i] = Fb[16 + l*3 + i];
        #pragma unroll
        for (int i = 0; i < 5; ++i) fv[4 + i] = Fb[64 + l*5 + i];
    }

    __syncthreads();   // s_cg (cross-wave) staged; covers s_y too

    float acc1[1] = {0.f};
    float acc3[3] = {0.f, 0.f, 0.f};
    float acc5[5] = {0.f, 0.f, 0.f, 0.f, 0.f};

    do_class<0,0, 0, 1>(l, eloc, wv, c4, rr, fv, acc1, R, s_cg, s_y, s_cgy, s_tmp, s_W);
    do_class<0,1, 1, 2>(l, eloc, wv, c4, rr, fv, acc1, R, s_cg, s_y, s_cgy, s_tmp, s_W);
    do_class<0,2, 2, 3>(l, eloc, wv, c4, rr, fv, acc1, R, s_cg, s_y, s_cgy, s_tmp, s_W);
    do_class<1,0, 3, 4>(l, eloc, wv, c4, rr, fv, acc3, R, s_cg, s_y, s_cgy, s_tmp, s_W);
    do_class<1,1, 4, 7>(l, eloc, wv, c4, rr, fv, acc3, R, s_cg, s_y, s_cgy, s_tmp, s_W);
    do_class<1,2, 7,10>(l, eloc, wv, c4, rr, fv, acc3, R, s_cg, s_y, s_cgy, s_tmp, s_W);
    do_class<2,0,10,11>(l, eloc, wv, c4, rr, fv, acc5, R, s_cg, s_y, s_cgy, s_tmp, s_W);
    do_class<2,1,11,14>(l, eloc, wv, c4, rr, fv, acc5, R, s_cg, s_y, s_cgy, s_tmp, s_W);
    do_class<2,2,14,19>(l, eloc, wv, c4, rr, fv, acc5, R, s_cg, s_y, s_cgy, s_tmp, s_W);

    // tail: coalesced plain stores, msg layout [j][16 lanes]
    if (act) {
        float* m = msg + (size_t)e * 144 + l;
        m[0*16] = acc1[0];
        #pragma unroll
        for (int o = 0; o < 3; ++o) m[(1+o)*16] = acc3[o];
        #pragma unroll
        for (int o = 0; o < 5; ++o) m[(4+o)*16] = acc5[o];
    }
}

// ---------------- Phase B: node gather-reduce (no atomics) ----------------
__global__ __launch_bounds__(BLK)
void se3_gather(const float* __restrict__ msg, const int* __restrict__ off,
                const int* __restrict__ eidx, const float* __restrict__ Nn,
                float* __restrict__ Out, const int nN)
{
    const int l = threadIdx.x & 15;
    const int g = threadIdx.x >> 4;
    const int n = blockIdx.x * 16 + g;
    if (n >= nN) return;

    const int i0 = off[n], i1 = off[n + 1];
    float s[9];
    #pragma unroll
    for (int j = 0; j < 9; ++j) s[j] = 0.f;

    for (int idx = i0; idx < i1; ++idx) {
        const int eid = eidx[idx];
        const float* m = msg + (size_t)eid * 144 + l;
        #pragma unroll
        for (int j = 0; j < 9; ++j) s[j] += m[j * 16];
    }

    const float nn = Nn[n];
    float* orow = Out + (size_t)n * 144;
    orow[l] = s[0] * nn;
    #pragma unroll
    for (int o = 0; o < 3; ++o) orow[16 + l*3 + o] = s[1+o] * nn;
    #pragma unroll
    for (int o = 0; o < 5; ++o) orow[64 + l*5 + o] = s[4+o] * nn;
}

// ---------------- CSR build (by destination) ----------------
__global__ void k_count(const int* __restrict__ Ma, int* __restrict__ cur, int E) {
    int e = blockIdx.x * blockDim.x + threadIdx.x;
    if (e < E) atomicAdd(&cur[Ma[e]], 1);
}

__global__ void k_scan(int* __restrict__ cur, int* __restrict__ off, int N) {
    __shared__ int part[BLK];
    const int t = threadIdx.x;
    const int K = (N + BLK - 1) / BLK;
    const int i0 = t * K, i1 = min(i0 + K, N);
    int s = 0;
    for (int i = i0; i < i1; ++i) s += cur[i];
    part[t] = s;
    __syncthreads();
    if (t == 0) {
        int a = 0;
        for (int j = 0; j < BLK; ++j) { int v = part[j]; part[j] = a; a += v; }
        off[N] = a;
    }
    __syncthreads();
    int a = part[t];
    for (int i = i0; i < i1; ++i) {
        int v = cur[i];
        off[i] = a;
        cur[i] = a;       // reuse as scatter cursor
        a += v;
    }
}

__global__ void k_scatter(const int* __restrict__ Ma, int* __restrict__ cur,
                          int* __restrict__ eidx, int E) {
    int e = blockIdx.x * blockDim.x + threadIdx.x;
    if (e < E) {
        int pos = atomicAdd(&cur[Ma[e]], 1);
        eidx[pos] = e;
    }
}

extern "C" void kernel_launch(void* const* d_in, const int* in_sizes, int n_in,
                              void* d_out, int out_size, void* d_ws, size_t ws_size,
                              hipStream_t stream) {
    const float* F   = (const float*)d_in[0];
    const float* R   = (const float*)d_in[1];
    const float* Ys  = (const float*)d_in[2];
    const float* Rad = (const float*)d_in[3];
    const float* cg  = (const float*)d_in[4];
    const float* Nn  = (const float*)d_in[5];
    const int*   Ma  = (const int*)d_in[6];
    const int*   Mb  = (const int*)d_in[7];
    float* Out = (float*)d_out;

    const int nE = in_sizes[6];   // edges
    const int nN = in_sizes[5];   // nodes

    // ws layout: [cur nN][off nN+1][eidx nE][pad][msg nE*144 floats]
    int* wsI  = (int*)d_ws;
    int* cur  = wsI;
    int* off  = wsI + nN;
    int* eidx = wsI + 2*nN + 1;
    size_t msgOff = ((size_t)(2*nN + 1 + nE) + 63) & ~(size_t)63;
    float* msg = (float*)d_ws + msgOff;

    hipMemsetAsync(cur, 0, (size_t)nN * sizeof(int), stream);
    k_count  <<<(nE + BLK - 1) / BLK, BLK, 0, stream>>>(Ma, cur, nE);
    k_scan   <<<1, BLK, 0, stream>>>(cur, off, nN);
    k_scatter<<<(nE + BLK - 1) / BLK, BLK, 0, stream>>>(Ma, cur, eidx, nE);

    se3_msg   <<<(nE + EPB - 1) / EPB, BLK, 0, stream>>>(F, R, Ys, Rad, cg, Mb, msg, nE);
    se3_gather<<<(nN + 15) / 16, BLK, 0, stream>>>(msg, off, eidx, Nn, Out, nN);
}

// Round 11
// 1122.814 us; speedup vs baseline: 2.3530x; 2.3530x over previous
//
#include <hip/hip_runtime.h>
#include <hip/hip_bf16.h>

#define NP   19
#define EPB  16
#define BLK  256
#define WST  260        // s_W row stride (words)
#define RSTRIDE 4864    // P_TOTAL columns in R

typedef __attribute__((ext_vector_type(8))) short bf16x8;
typedef __attribute__((ext_vector_type(4))) float f32x4;

// ---- per-path metadata (p is wave-uniform -> scalar loads) ----
__device__ const int   d_io[NP]  = {0,0,0, 1,1,1,1,1,1,1, 2,2,2,2, 2,2,2,2,2};
__device__ const int   d_ii[NP]  = {0,1,2, 0,1,1,1,2,2,2, 0,1,1,1, 2,2,2,2,2};
__device__ const int   d_lf[NP]  = {0,1,2, 1,0,1,2,1,2,3, 2,1,2,3, 0,1,2,3,4};
__device__ const int   d_cgb[NP] = {0,1,10, 35,44,53,80,125,170,245, 350,375,420,495, 600,625,700,825,1000};
__device__ const float d_nrm[5]  = {1.0f, 0.57735026918962576f, 0.44721359549995794f,
                                    0.37796447300922722f, 0.33333333333333333f};
__device__ const int   d_fo[3]   = {0, 1, 4};   // F-slice offset per ii
__device__ const int   d_ob[3]   = {0, 1, 4};   // msg 9-slot base per io

// ---- setup: swizzle R into MFMA B-fragment order, bf16, K 10->32 zero-padded ----
// Rt[((p*16 + t)*64 + lane)*8 + j] = bf16(R[r][p*256 + 16t + (lane&15)]), r=(lane>>4)*8+j
__global__ void k_rt(const float* __restrict__ R, unsigned short* __restrict__ Rt) {
    int i = blockIdx.x * blockDim.x + threadIdx.x;     // over NP*16*64*8
    if (i >= NP * 16 * 64 * 8) return;
    const int j    = i & 7;
    const int lane = (i >> 3) & 63;
    const int t    = (i >> 9) & 15;
    const int p    = i >> 13;
    const int r    = (lane >> 4) * 8 + j;
    const int col  = p * 256 + 16 * t + (lane & 15);
    float v = (r < 10) ? R[r * RSTRIDE + col] : 0.f;
    __hip_bfloat16 h = __float2bfloat16(v);
    Rt[i] = *reinterpret_cast<unsigned short*>(&h);
}

// ---------------- Phase A: edge-major, small-code path loop (R9 structure) ----------------
__global__ __launch_bounds__(BLK, 3)
void se3_msg(const float* __restrict__ F,
             const float* __restrict__ Ys, const float* __restrict__ Rad,
             const float* __restrict__ cg, const unsigned short* __restrict__ Rt,
             const int* __restrict__ Mb,
             float* __restrict__ msg, const int nE)
{
    __shared__ float s_cg [1225];
    __shared__ float s_y  [EPB][26];
    __shared__ float s_Fv [EPB*16*9];
    __shared__ float s_cgy[EPB][28];
    __shared__ float s_tmp[EPB*84];
    __shared__ float s_W  [EPB*WST];
    __shared__ float s_msg[EPB*144];

    const int tid  = threadIdx.x;
    const int l    = tid & 15;
    const int eloc = tid >> 4;
    const int lane = tid & 63;
    const int wv   = tid >> 6;
    const int e    = blockIdx.x * EPB + eloc;
    const bool act = (e < nE);
    const int  es  = act ? e : 0;

    // ---- setup staging (once per block) ----
    for (int t = tid; t < 1225; t += BLK) s_cg[t] = cg[t];

    for (int k = l; k < 25; k += 16) s_y[eloc][k] = Ys[(size_t)es*25 + k];

    {
        const int b = Mb[es];
        const float* Fb = F + (size_t)b * 144;
        float* fv = &s_Fv[(eloc*16 + l) * 9];
        fv[0] = Fb[l];
        #pragma unroll
        for (int i = 0; i < 3; ++i) fv[1 + i] = Fb[16 + l*3 + i];
        #pragma unroll
        for (int i = 0; i < 5; ++i) fv[4 + i] = Fb[64 + l*5 + i];
    }
    #pragma unroll
    for (int j = 0; j < 9; ++j) s_msg[eloc*144 + j*16 + l] = 0.f;

    // ---- A-fragment (built once): rad[m=lane&15][k=(lane>>4)*8+j] as bf16,
    //      K zero-padded 10->32, inactive edges -> 0 (message contributes 0) ----
    bf16x8 afrag;
    {
        const int m  = lane & 15;
        const int k0 = (lane >> 4) * 8;
        const int ge = blockIdx.x * EPB + m;
        const bool a = (ge < nE);
        const float* rp = Rad + (size_t)(a ? ge : 0) * 10;
        #pragma unroll
        for (int j = 0; j < 8; ++j) {
            const int k = k0 + j;
            float v = (a && k < 10) ? rp[k] : 0.f;
            __hip_bfloat16 h = __float2bfloat16(v);
            afrag[j] = *reinterpret_cast<short*>(&h);
        }
    }

    __syncthreads();

    // ---- THE path loop: small body, executed 19x from I$ ----
    #pragma unroll 1
    for (int p = 0; p < NP; ++p) {
        const int io = d_io[p], ii = d_ii[p], lf = d_lf[p];
        const int dO = 2*io + 1, dI = 2*ii + 1, dF = 2*lf + 1;
        const int nOI = dO * dI;
        const int yb  = lf * lf;
        const int cgb = d_cgb[p];
        const int fo  = d_fo[ii];
        const int ob  = d_ob[io];
        const float nrm = d_nrm[lf];

        // stage 1a (MFMA): W(16e x 256c) = rad(16x10) @ R_p(10x256).
        // wave wv owns col-tiles 4wv..4wv+3; D layout: col=lane&15, row=(lane>>4)*4+reg.
        {
            const unsigned short* rtp = Rt + ((size_t)p*16 + 4*wv)*512 + lane*8;
            #pragma unroll
            for (int tt = 0; tt < 4; ++tt) {
                const bf16x8 bfrag = *reinterpret_cast<const bf16x8*>(rtp + tt*512);
                f32x4 d = __builtin_amdgcn_mfma_f32_16x16x32_bf16(
                              afrag, bfrag, (f32x4){0.f,0.f,0.f,0.f}, 0, 0, 0);
                const int t4   = 4*wv + tt;
                const int base = ((lane >> 4)*4)*WST + 16*t4 + (lane & 15);
                #pragma unroll
                for (int r = 0; r < 4; ++r)
                    s_W[base + r*WST] = d[r];
            }
        }

        // stage 1b: cgY[o,i] = nrm * sum_f cg[o,i,f] * y[yb+f]  (16 lanes cover nOI)
        for (int j0 = 0; j0 < nOI; j0 += 16) {
            const int j = j0 + l;
            if (j < nOI) {
                float s = 0.f;
                const float* cgp = &s_cg[cgb + j*dF];
                const float* yp  = &s_y[eloc][yb];
                for (int f = 0; f < dF; ++f) s += cgp[f] * yp[f];
                s_cgy[eloc][j] = s * nrm;
            }
        }
        __syncthreads();

        // stage 2: tmp[v,o] = sum_i F[v, fo+i] * cgY[o*dI+i]   (lane = v)
        {
            const float* fv = &s_Fv[(eloc*16 + l) * 9 + fo];
            for (int o = 0; o < dO; ++o) {
                float t = 0.f;
                const float* cy = &s_cgy[eloc][o*dI];
                for (int i = 0; i < dI; ++i) t += fv[i] * cy[i];
                s_tmp[eloc*84 + o*16 + l] = t;
            }
        }
        __syncthreads();

        // stage 3: msg[ob+o][w] += sum_v W[w,v] * tmp[v,o]   (lane = w)
        {
            const float* Wrow = &s_W[eloc*WST + 16*l];
            const float4 w0 = *reinterpret_cast<const float4*>(Wrow);
            const float4 w1 = *reinterpret_cast<const float4*>(Wrow + 4);
            const float4 w2 = *reinterpret_cast<const float4*>(Wrow + 8);
            const float4 w3 = *reinterpret_cast<const float4*>(Wrow + 12);
            for (int o = 0; o < dO; ++o) {
                const float4* tq = reinterpret_cast<const float4*>(&s_tmp[eloc*84 + o*16]);
                const float4 t0 = tq[0], t1 = tq[1], t2 = tq[2], t3 = tq[3];
                float s = w0.x*t0.x + w0.y*t0.y + w0.z*t0.z + w0.w*t0.w
                        + w1.x*t1.x + w1.y*t1.y + w1.z*t1.z + w1.w*t1.w
                        + w2.x*t2.x + w2.y*t2.y + w2.z*t2.z + w2.w*t2.w
                        + w3.x*t3.x + w3.y*t3.y + w3.z*t3.z + w3.w*t3.w;
                s_msg[eloc*144 + (ob + o)*16 + l] += s;   // lane-private column
            }
        }
        __syncthreads();   // WAR: next path rewrites s_W/s_cgy/s_tmp
    }

    // tail: coalesced plain stores
    if (act) {
        float* m = msg + (size_t)e * 144 + l;
        #pragma unroll
        for (int j = 0; j < 9; ++j) m[j * 16] = s_msg[eloc*144 + j*16 + l];
    }
}

// ---------------- Phase B: node gather-reduce (no atomics) ----------------
__global__ __launch_bounds__(BLK)
void se3_gather(const float* __restrict__ msg, const int* __restrict__ off,
                const int* __restrict__ eidx, const float* __restrict__ Nn,
                float* __restrict__ Out, const int nN)
{
    const int l = threadIdx.x & 15;
    const int g = threadIdx.x >> 4;
    const int n = blockIdx.x * 16 + g;
    if (n >= nN) return;

    const int i0 = off[n], i1 = off[n + 1];
    float s[9];
    #pragma unroll
    for (int j = 0; j < 9; ++j) s[j] = 0.f;

    for (int idx = i0; idx < i1; ++idx) {
        const int eid = eidx[idx];
        const float* m = msg + (size_t)eid * 144 + l;
        #pragma unroll
        for (int j = 0; j < 9; ++j) s[j] += m[j * 16];
    }

    const float nn = Nn[n];
    float* orow = Out + (size_t)n * 144;
    orow[l] = s[0] * nn;
    #pragma unroll
    for (int o = 0; o < 3; ++o) orow[16 + l*3 + o] = s[1+o] * nn;
    #pragma unroll
    for (int o = 0; o < 5; ++o) orow[64 + l*5 + o] = s[4+o] * nn;
}

// ---------------- CSR build (by destination) ----------------
__global__ void k_count(const int* __restrict__ Ma, int* __restrict__ cur, int E) {
    int e = blockIdx.x * blockDim.x + threadIdx.x;
    if (e < E) atomicAdd(&cur[Ma[e]], 1);
}

__global__ void k_scan(int* __restrict__ cur, int* __restrict__ off, int N) {
    __shared__ int part[BLK];
    const int t = threadIdx.x;
    const int K = (N + BLK - 1) / BLK;
    const int i0 = t * K, i1 = min(i0 + K, N);
    int s = 0;
    for (int i = i0; i < i1; ++i) s += cur[i];
    part[t] = s;
    __syncthreads();
    if (t == 0) {
        int a = 0;
        for (int j = 0; j < BLK; ++j) { int v = part[j]; part[j] = a; a += v; }
        off[N] = a;
    }
    __syncthreads();
    int a = part[t];
    for (int i = i0; i < i1; ++i) {
        int v = cur[i];
        off[i] = a;
        cur[i] = a;       // reuse as scatter cursor
        a += v;
    }
}

__global__ void k_scatter(const int* __restrict__ Ma, int* __restrict__ cur,
                          int* __restrict__ eidx, int E) {
    int e = blockIdx.x * blockDim.x + threadIdx.x;
    if (e < E) {
        int pos = atomicAdd(&cur[Ma[e]], 1);
        eidx[pos] = e;
    }
}

extern "C" void kernel_launch(void* const* d_in, const int* in_sizes, int n_in,
                              void* d_out, int out_size, void* d_ws, size_t ws_size,
                              hipStream_t stream) {
    const float* F   = (const float*)d_in[0];
    const float* R   = (const float*)d_in[1];
    const float* Ys  = (const float*)d_in[2];
    const float* Rad = (const float*)d_in[3];
    const float* cg  = (const float*)d_in[4];
    const float* Nn  = (const float*)d_in[5];
    const int*   Ma  = (const int*)d_in[6];
    const int*   Mb  = (const int*)d_in[7];
    float* Out = (float*)d_out;

    const int nE = in_sizes[6];   // edges
    const int nN = in_sizes[5];   // nodes

    // ws layout: [cur nN][off nN+1][eidx nE][pad][msg nE*144 f32][pad][Rt NP*16*64*8 bf16]
    int* wsI  = (int*)d_ws;
    int* cur  = wsI;
    int* off  = wsI + nN;
    int* eidx = wsI + 2*nN + 1;
    size_t msgOff = ((size_t)(2*nN + 1 + nE) + 63) & ~(size_t)63;
    float* msg = (float*)d_ws + msgOff;
    size_t rtOff = ((msgOff + (size_t)nE * 144) + 63) & ~(size_t)63;
    unsigned short* Rt = (unsigned short*)((float*)d_ws + rtOff);

    hipMemsetAsync(cur, 0, (size_t)nN * sizeof(int), stream);
    k_count  <<<(nE + BLK - 1) / BLK, BLK, 0, stream>>>(Ma, cur, nE);
    k_scan   <<<1, BLK, 0, stream>>>(cur, off, nN);
    k_scatter<<<(nE + BLK - 1) / BLK, BLK, 0, stream>>>(Ma, cur, eidx, nE);
    k_rt     <<<(NP*16*64*8 + BLK - 1) / BLK, BLK, 0, stream>>>(R, Rt);

    se3_msg   <<<(nE + EPB - 1) / EPB, BLK, 0, stream>>>(F, Ys, Rad, cg, Rt, Mb, msg, nE);
    se3_gather<<<(nN + 15) / 16, BLK, 0, stream>>>(msg, off, eidx, Nn, Out, nN);
}

// Round 12
// 864.026 us; speedup vs baseline: 3.0578x; 1.2995x over previous
//
#include <hip/hip_runtime.h>
#include <hip/hip_bf16.h>

#define NP   19
#define EPB  16
#define BLK  256
#define RSTRIDE 4864
#define WS   24            // w/n stride within an edge row (bf16 units); 24 dwords*? -> 12 dwords, %32 spreads 2-way
#define ES   392           // e stride (bf16): >=16*24=384; 196 dwords %32=4 -> elocs spread banks
#define PBS  (16*ES)       // path-parity buffer stride (bf16 units)

typedef __attribute__((ext_vector_type(8))) short bf16x8;
typedef __attribute__((ext_vector_type(4))) float f32x4;

// ---- per-path metadata (p wave-uniform -> scalar loads) ----
__device__ const int   d_io[NP]  = {0,0,0, 1,1,1,1,1,1,1, 2,2,2,2, 2,2,2,2,2};
__device__ const int   d_ii[NP]  = {0,1,2, 0,1,1,1,2,2,2, 0,1,1,1, 2,2,2,2,2};
__device__ const int   d_lf[NP]  = {0,1,2, 1,0,1,2,1,2,3, 2,1,2,3, 0,1,2,3,4};
__device__ const int   d_cgb[NP] = {0,1,10, 35,44,53,80,125,170,245, 350,375,420,495, 600,625,700,825,1000};
__device__ const float d_nrm5[5] = {1.0f, 0.57735026918962576f, 0.44721359549995794f,
                                    0.37796447300922722f, 0.33333333333333333f};

__device__ __forceinline__ unsigned short to_bf16(float v) {
    __hip_bfloat16 h = __float2bfloat16(v);
    return *reinterpret_cast<unsigned short*>(&h);
}

// ---- setup: swizzle R into MFMA-1 B-fragment order, bf16, K 10->32 zero-padded ----
__global__ void k_rt(const float* __restrict__ R, unsigned short* __restrict__ Rt) {
    int i = blockIdx.x * blockDim.x + threadIdx.x;     // over NP*16*64*8
    if (i >= NP * 16 * 64 * 8) return;
    const int j    = i & 7;
    const int lane = (i >> 3) & 63;
    const int t    = (i >> 9) & 15;
    const int p    = i >> 13;
    const int r    = (lane >> 4) * 8 + j;
    const int col  = p * 256 + 16 * t + (lane & 15);
    float v = (r < 10) ? R[r * RSTRIDE + col] : 0.f;
    Rt[i] = to_bf16(v);
}

// ---------------- Phase A: edge-major; W-GEMM and msg-GEMM both on MFMA ----------------
__global__ __launch_bounds__(BLK, 3)
void se3_msg(const float* __restrict__ F,
             const float* __restrict__ Ys, const float* __restrict__ Rad,
             const float* __restrict__ cg, const unsigned short* __restrict__ Rt,
             const int* __restrict__ Mb,
             float* __restrict__ msg, const int nE)
{
    __shared__ __align__(16) unsigned short s_Wa[2 * PBS];  // Wstack A-frag  [pb][e][w][v]
    __shared__ __align__(16) unsigned short s_tB[2 * PBS];  // tmpstack B-frag [pb][e][n][v]
    __shared__ float s_cgy[EPB][28];

    const int tid  = threadIdx.x;
    const int l    = tid & 15;
    const int eloc = tid >> 4;
    const int lane = tid & 63;
    const int wv   = tid >> 6;
    const int q    = lane >> 4;
    const int n16  = lane & 15;
    const int e    = blockIdx.x * EPB + eloc;
    const bool act = (e < nE);
    const int  es  = act ? e : 0;

    // F slice -> registers (compile-time indexed)
    float fv[9];
    {
        const int b = Mb[es];
        const float* Fb = F + (size_t)b * 144;
        fv[0] = Fb[l];
        #pragma unroll
        for (int i = 0; i < 3; ++i) fv[1 + i] = Fb[16 + l*3 + i];
        #pragma unroll
        for (int i = 0; i < 5; ++i) fv[4 + i] = Fb[64 + l*5 + i];
    }
    // Ys row -> registers (switch(lf) gives compile-time indices)
    float y[25];
    {
        const float* yr = Ys + (size_t)es * 25;
        #pragma unroll
        for (int k = 0; k < 25; ++k) y[k] = yr[k];
    }
    // MFMA-1 A-fragment: rad[m=edge][k=r], K zero-padded 10->32; inactive edges -> 0
    bf16x8 afrag;
    {
        const int m  = n16;
        const int k0 = q * 8;
        const int ge = blockIdx.x * EPB + m;
        const bool a = (ge < nE);
        const float* rp = Rad + (size_t)(a ? ge : 0) * 10;
        #pragma unroll
        for (int j = 0; j < 8; ++j) {
            const int k = k0 + j;
            afrag[j] = (short)((a && k < 10) ? to_bf16(rp[k]) : (unsigned short)0);
        }
    }

    f32x4 D[4];
    #pragma unroll
    for (int ee = 0; ee < 4; ++ee) D[ee] = (f32x4){0.f,0.f,0.f,0.f};

    // ---- K-block loop: 10 x (2 paths staged -> 1 MFMA-2 K-step per edge) ----
    #pragma unroll 1
    for (int kb = 0; kb < 10; ++kb) {
        #pragma unroll
        for (int pb = 0; pb < 2; ++pb) {
            const int p = 2*kb + pb;
            unsigned short* wb = &s_Wa[pb * PBS];
            if (p < NP) {
                // MFMA-1: W_p(16e x 256c) = rad @ R_p; wave owns w-tiles 4wv..4wv+3.
                // D[row=e=q*4+r, col=v=n16] -> store bf16 A-layout [e][w][v].
                const unsigned short* rtp = Rt + ((size_t)p*16 + 4*wv)*512 + lane*8;
                #pragma unroll
                for (int tt = 0; tt < 4; ++tt) {
                    const bf16x8 bfrag = *reinterpret_cast<const bf16x8*>(rtp + tt*512);
                    f32x4 d = __builtin_amdgcn_mfma_f32_16x16x32_bf16(
                                  afrag, bfrag, (f32x4){0.f,0.f,0.f,0.f}, 0, 0, 0);
                    const int w = 4*wv + tt;
                    #pragma unroll
                    for (int r = 0; r < 4; ++r)
                        wb[(q*4 + r)*ES + w*WS + n16] = to_bf16(d[r]);
                }

                // path metadata (scalar)
                const int io = d_io[p], ii = d_ii[p], lf = d_lf[p], cgb = d_cgb[p];
                const int dO = 2*io + 1, dI = 2*ii + 1, dF = 2*lf + 1;
                const int nOI = dO * dI;
                const int ob  = (io == 0) ? 0 : (io == 1) ? 1 : 4;
                const float nrm = d_nrm5[lf];

                // cgY[j=(o,i)] cooperative across the 16 lanes of eloc; cg from global (L1-hot)
                for (int j0 = 0; j0 < nOI; j0 += 16) {
                    const int j = j0 + l;
                    if (j < nOI) {
                        const float* cgp = cg + cgb + j*dF;
                        float s;
                        switch (lf) {   // wave-uniform
                          case 0:  s = cgp[0]*y[0]; break;
                          case 1:  s = cgp[0]*y[1]+cgp[1]*y[2]+cgp[2]*y[3]; break;
                          case 2:  s = cgp[0]*y[4]+cgp[1]*y[5]+cgp[2]*y[6]+cgp[3]*y[7]
                                     + cgp[4]*y[8]; break;
                          case 3:  s = cgp[0]*y[9]+cgp[1]*y[10]+cgp[2]*y[11]+cgp[3]*y[12]
                                     + cgp[4]*y[13]+cgp[5]*y[14]+cgp[6]*y[15]; break;
                          default: s = cgp[0]*y[16]+cgp[1]*y[17]+cgp[2]*y[18]+cgp[3]*y[19]
                                     + cgp[4]*y[20]+cgp[5]*y[21]+cgp[6]*y[22]+cgp[7]*y[23]
                                     + cgp[8]*y[24]; break;
                        }
                        s_cgy[eloc][j] = s * nrm;
                    }
                }
                __asm__ volatile("" ::: "memory");   // cgY visible (intra-wave exchange)

                // tmp[v=l, o] -> B-frag bf16 [e][n=ob+o][v]; zero the other n columns
                unsigned short* tb = &s_tB[pb * PBS + eloc*ES + l];
                #pragma unroll
                for (int n = 0; n < 16; ++n) tb[n * WS] = 0;
                for (int o = 0; o < dO; ++o) {
                    const float* cy = &s_cgy[eloc][o*dI];
                    float t;
                    if (ii == 0)      t = fv[0]*cy[0];
                    else if (ii == 1) t = fv[1]*cy[0] + fv[2]*cy[1] + fv[3]*cy[2];
                    else              t = fv[4]*cy[0] + fv[5]*cy[1] + fv[6]*cy[2]
                                        + fv[7]*cy[3] + fv[8]*cy[4];
                    tb[(ob + o) * WS] = to_bf16(t);
                }
                __asm__ volatile("" ::: "memory");   // WAR on s_cgy before next pb
            } else {
                // p == 19 pad: zero our s_Wa slots (A==0 -> contributes nothing)
                #pragma unroll
                for (int tt = 0; tt < 4; ++tt)
                    #pragma unroll
                    for (int r = 0; r < 4; ++r)
                        wb[(q*4 + r)*ES + (4*wv + tt)*WS + n16] = 0;
            }
        }
        __syncthreads();   // W (cross-wave w-tiles) + tmp staged for this K-block

        // MFMA-2 K-step: msg_e(16w x 16n) += Wstack_e(16x32) @ tmpstack_e(32x16)
        // A[m=w=n16][k=q*8+j]; k -> (pb=q>>1, v=(q&1)*8+j). B symmetric with n=o.
        {
            const int pb2 = q >> 1;
            const int vh  = (q & 1) * 8;
            #pragma unroll
            for (int ee = 0; ee < 4; ++ee) {
                const int eK = 4*wv + ee;
                const bf16x8 Af = *reinterpret_cast<const bf16x8*>(
                                      &s_Wa[pb2*PBS + eK*ES + n16*WS + vh]);
                const bf16x8 Bf = *reinterpret_cast<const bf16x8*>(
                                      &s_tB[pb2*PBS + eK*ES + n16*WS + vh]);
                D[ee] = __builtin_amdgcn_mfma_f32_16x16x32_bf16(Af, Bf, D[ee], 0, 0, 0);
            }
        }
        __syncthreads();   // WAR: next K-block rewrites s_Wa/s_tB
    }

    // epilogue: D[row=w=q*4+r, col=oflat=n16] -> msg[e][oflat*16 + w], float4 stores
    if (n16 < 9) {
        #pragma unroll
        for (int ee = 0; ee < 4; ++ee) {
            const int eg = blockIdx.x * EPB + 4*wv + ee;
            if (eg < nE) {
                float* mp = msg + (size_t)eg * 144 + n16*16 + q*4;
                float4 v4; v4.x = D[ee][0]; v4.y = D[ee][1]; v4.z = D[ee][2]; v4.w = D[ee][3];
                *reinterpret_cast<float4*>(mp) = v4;
            }
        }
    }
}

// ---------------- Phase B: node gather-reduce (no atomics) ----------------
__global__ __launch_bounds__(BLK)
void se3_gather(const float* __restrict__ msg, const int* __restrict__ off,
                const int* __restrict__ eidx, const float* __restrict__ Nn,
                float* __restrict__ Out, const int nN)
{
    const int l = threadIdx.x & 15;
    const int g = threadIdx.x >> 4;
    const int n = blockIdx.x * 16 + g;
    if (n >= nN) return;

    const int i0 = off[n], i1 = off[n + 1];
    float s[9];
    #pragma unroll
    for (int j = 0; j < 9; ++j) s[j] = 0.f;

    for (int idx = i0; idx < i1; ++idx) {
        const int eid = eidx[idx];
        const float* m = msg + (size_t)eid * 144 + l;
        #pragma unroll
        for (int j = 0; j < 9; ++j) s[j] += m[j * 16];
    }

    const float nn = Nn[n];
    float* orow = Out + (size_t)n * 144;
    orow[l] = s[0] * nn;
    #pragma unroll
    for (int o = 0; o < 3; ++o) orow[16 + l*3 + o] = s[1+o] * nn;
    #pragma unroll
    for (int o = 0; o < 5; ++o) orow[64 + l*5 + o] = s[4+o] * nn;
}

// ---------------- CSR build (by destination) ----------------
__global__ void k_count(const int* __restrict__ Ma, int* __restrict__ cur, int E) {
    int e = blockIdx.x * blockDim.x + threadIdx.x;
    if (e < E) atomicAdd(&cur[Ma[e]], 1);
}

__global__ void k_scan(int* __restrict__ cur, int* __restrict__ off, int N) {
    __shared__ int part[BLK];
    const int t = threadIdx.x;
    const int K = (N + BLK - 1) / BLK;
    const int i0 = t * K, i1 = min(i0 + K, N);
    int s = 0;
    for (int i = i0; i < i1; ++i) s += cur[i];
    part[t] = s;
    __syncthreads();
    if (t == 0) {
        int a = 0;
        for (int j = 0; j < BLK; ++j) { int v = part[j]; part[j] = a; a += v; }
        off[N] = a;
    }
    __syncthreads();
    int a = part[t];
    for (int i = i0; i < i1; ++i) {
        int v = cur[i];
        off[i] = a;
        cur[i] = a;       // reuse as scatter cursor
        a += v;
    }
}

__global__ void k_scatter(const int* __restrict__ Ma, int* __restrict__ cur,
                          int* __restrict__ eidx, int E) {
    int e = blockIdx.x * blockDim.x + threadIdx.x;
    if (e < E) {
        int pos = atomicAdd(&cur[Ma[e]], 1);
        eidx[pos] = e;
    }
}

extern "C" void kernel_launch(void* const* d_in, const int* in_sizes, int n_in,
                              void* d_out, int out_size, void* d_ws, size_t ws_size,
                              hipStream_t stream) {
    const float* F   = (const float*)d_in[0];
    const float* R   = (const float*)d_in[1];
    const float* Ys  = (const float*)d_in[2];
    const float* Rad = (const float*)d_in[3];
    const float* cg  = (const float*)d_in[4];
    const float* Nn  = (const float*)d_in[5];
    const int*   Ma  = (const int*)d_in[6];
    const int*   Mb  = (const int*)d_in[7];
    float* Out = (float*)d_out;

    const int nE = in_sizes[6];   // edges
    const int nN = in_sizes[5];   // nodes

    // ws layout: [cur nN][off nN+1][eidx nE][pad][msg nE*144 f32][pad][Rt NP*16*64*8 bf16]
    int* wsI  = (int*)d_ws;
    int* cur  = wsI;
    int* off  = wsI + nN;
    int* eidx = wsI + 2*nN + 1;
    size_t msgOff = ((size_t)(2*nN + 1 + nE) + 63) & ~(size_t)63;
    float* msg = (float*)d_ws + msgOff;
    size_t rtOff = ((msgOff + (size_t)nE * 144) + 63) & ~(size_t)63;
    unsigned short* Rt = (unsigned short*)((float*)d_ws + rtOff);

    hipMemsetAsync(cur, 0, (size_t)nN * sizeof(int), stream);
    k_count  <<<(nE + BLK - 1) / BLK, BLK, 0, stream>>>(Ma, cur, nE);
    k_scan   <<<1, BLK, 0, stream>>>(cur, off, nN);
    k_scatter<<<(nE + BLK - 1) / BLK, BLK, 0, stream>>>(Ma, cur, eidx, nE);
    k_rt     <<<(NP*16*64*8 + BLK - 1) / BLK, BLK, 0, stream>>>(R, Rt);

    se3_msg   <<<(nE + EPB - 1) / EPB, BLK, 0, stream>>>(F, Ys, Rad, cg, Rt, Mb, msg, nE);
    se3_gather<<<(nN + 15) / 16, BLK, 0, stream>>>(msg, off, eidx, Nn, Out, nN);
}

// Round 13
// 744.859 us; speedup vs baseline: 3.5470x; 1.1600x over previous
//
#include <hip/hip_runtime.h>
#include <hip/hip_bf16.h>

#define NP   19
#define EPB  16
#define BLK  256
#define RSTRIDE 4864
#define WS   24            // w/n stride within an edge row (bf16 units)
#define ES   392           // e stride (bf16): 16*24 + 8, keeps 16B alignment
#define PBS  (16*ES)       // K-half buffer stride (bf16 units)

typedef __attribute__((ext_vector_type(8))) short bf16x8;
typedef __attribute__((ext_vector_type(4))) float f32x4;

// ---- per-path metadata (p wave-uniform -> scalar loads) ----
__device__ const int   d_io[NP]  = {0,0,0, 1,1,1,1,1,1,1, 2,2,2,2, 2,2,2,2,2};
__device__ const int   d_ii[NP]  = {0,1,2, 0,1,1,1,2,2,2, 0,1,1,1, 2,2,2,2,2};
__device__ const int   d_lf[NP]  = {0,1,2, 1,0,1,2,1,2,3, 2,1,2,3, 0,1,2,3,4};
__device__ const int   d_cgb[NP] = {0,1,10, 35,44,53,80,125,170,245, 350,375,420,495, 600,625,700,825,1000};
__device__ const float d_nrm5[5] = {1.0f, 0.57735026918962576f, 0.44721359549995794f,
                                    0.37796447300922722f, 0.33333333333333333f};

__device__ __forceinline__ unsigned short to_bf16(float v) {
    __hip_bfloat16 h = __float2bfloat16(v);
    return *reinterpret_cast<unsigned short*>(&h);
}

// ---- setup: swizzle R into MFMA fragment order (A and B index maps identical),
//      bf16, K 10->32 zero-padded ----
__global__ void k_rt(const float* __restrict__ R, unsigned short* __restrict__ Rt) {
    int i = blockIdx.x * blockDim.x + threadIdx.x;     // over NP*16*64*8
    if (i >= NP * 16 * 64 * 8) return;
    const int j    = i & 7;
    const int lane = (i >> 3) & 63;
    const int t    = (i >> 9) & 15;
    const int p    = i >> 13;
    const int r    = (lane >> 4) * 8 + j;
    const int col  = p * 256 + 16 * t + (lane & 15);
    float v = (r < 10) ? R[r * RSTRIDE + col] : 0.f;
    Rt[i] = to_bf16(v);
}

// ---------------- Phase A: edge-major; W-GEMM and msg-GEMM both on MFMA ----------------
__global__ __launch_bounds__(BLK, 3)
void se3_msg(const float* __restrict__ F,
             const float* __restrict__ Ys, const float* __restrict__ Rad,
             const float* __restrict__ cg, const unsigned short* __restrict__ Rt,
             const int* __restrict__ Mb,
             float* __restrict__ msg, const int nE)
{
    __shared__ __align__(16) unsigned short s_Wa[2 * PBS];  // Wstack A-frag  [kh][e][w][v]
    __shared__ __align__(16) unsigned short s_tB[2 * PBS];  // tmpstack B-frag [kh][e][n][v]
    __shared__ float s_cgy[EPB][40];                        // cgY, o-rows padded to 8

    const int tid  = threadIdx.x;
    const int l    = tid & 15;
    const int eloc = tid >> 4;
    const int lane = tid & 63;
    const int wv   = tid >> 6;
    const int q    = lane >> 4;
    const int n16  = lane & 15;
    const int e    = blockIdx.x * EPB + eloc;
    const bool act = (e < nE);
    const int  es  = act ? e : 0;

    // F slice -> registers (compile-time indexed)
    float fv[9];
    {
        const int b = Mb[es];
        const float* Fb = F + (size_t)b * 144;
        fv[0] = Fb[l];
        #pragma unroll
        for (int i = 0; i < 3; ++i) fv[1 + i] = Fb[16 + l*3 + i];
        #pragma unroll
        for (int i = 0; i < 5; ++i) fv[4 + i] = Fb[64 + l*5 + i];
    }
    // Ys row -> registers
    float y[25];
    {
        const float* yr = Ys + (size_t)es * 25;
        #pragma unroll
        for (int k = 0; k < 25; ++k) y[k] = yr[k];
    }
    // radii fragment (B operand of MFMA-1): B[k=r][n=e], K zero-padded 10->32
    bf16x8 radfrag;
    {
        const int m  = n16;
        const int k0 = q * 8;
        const int ge = blockIdx.x * EPB + m;
        const bool a = (ge < nE);
        const float* rp = Rad + (size_t)(a ? ge : 0) * 10;
        #pragma unroll
        for (int j = 0; j < 8; ++j) {
            const int k = k0 + j;
            radfrag[j] = (short)((a && k < 10) ? to_bf16(rp[k]) : (unsigned short)0);
        }
    }

    // tb one-time zero (maintained incrementally afterwards)
    {
        unsigned short* tb0 = &s_tB[eloc*ES + l];
        #pragma unroll
        for (int n = 0; n < 16; ++n) { tb0[n*WS] = 0; tb0[PBS + n*WS] = 0; }
    }

    f32x4 D[4];
    #pragma unroll
    for (int ee = 0; ee < 4; ++ee) D[ee] = (f32x4){0.f,0.f,0.f,0.f};

    // ---- K-block loop: 10 x (2 paths staged -> 1 MFMA-2 K-step per edge) ----
    #pragma unroll 1
    for (int kb = 0; kb < 10; ++kb) {
        #pragma unroll
        for (int pb = 0; pb < 2; ++pb) {
            const int p = 2*kb + pb;
            if (p < NP) {
                // MFMA-1 (swapped): D = R_p^T(16c x 32k) @ rad^T(32k x 16e)
                // D[row=c_in_tile=q*4+r][col=e=n16]; 4 rows = 4 consecutive v -> b64 pack.
                const unsigned short* rtp = Rt + ((size_t)p*16 + 4*wv)*512 + lane*8;
                #pragma unroll
                for (int tt = 0; tt < 4; ++tt) {
                    const bf16x8 rfrag = *reinterpret_cast<const bf16x8*>(rtp + tt*512);
                    f32x4 d = __builtin_amdgcn_mfma_f32_16x16x32_bf16(
                                  rfrag, radfrag, (f32x4){0.f,0.f,0.f,0.f}, 0, 0, 0);
                    short4 pk;
                    pk.x = (short)to_bf16(d[0]); pk.y = (short)to_bf16(d[1]);
                    pk.z = (short)to_bf16(d[2]); pk.w = (short)to_bf16(d[3]);
                    *reinterpret_cast<short4*>(
                        &s_Wa[pb*PBS + n16*ES + (4*wv + tt)*WS + q*4]) = pk;
                }

                // path metadata (scalar)
                const int io = d_io[p], ii = d_ii[p], lf = d_lf[p], cgb = d_cgb[p];
                const int dO = 2*io + 1, dI = 2*ii + 1, dF = 2*lf + 1;
                const int nOI = dO * dI;
                const int ob  = (io == 0) ? 0 : (io == 1) ? 1 : 4;
                const float nrm = d_nrm5[lf];

                // cgY cooperative (16 lanes of eloc); cg from global (L1-hot);
                // store at [o*8+i] so tmp stage can read o-rows as float4.
                for (int j0 = 0; j0 < nOI; j0 += 16) {
                    const int j = j0 + l;
                    if (j < nOI) {
                        int o, i;
                        if (dI == 1)      { o = j;     i = 0;         }
                        else if (dI == 3) { o = j / 3; i = j - 3*o;   }
                        else              { o = j / 5; i = j - 5*o;   }
                        const float* cgp = cg + cgb + j*dF;
                        float s;
                        switch (lf) {   // wave-uniform
                          case 0:  s = cgp[0]*y[0]; break;
                          case 1:  s = cgp[0]*y[1]+cgp[1]*y[2]+cgp[2]*y[3]; break;
                          case 2:  s = cgp[0]*y[4]+cgp[1]*y[5]+cgp[2]*y[6]+cgp[3]*y[7]
                                     + cgp[4]*y[8]; break;
                          case 3:  s = cgp[0]*y[9]+cgp[1]*y[10]+cgp[2]*y[11]+cgp[3]*y[12]
                                     + cgp[4]*y[13]+cgp[5]*y[14]+cgp[6]*y[15]; break;
                          default: s = cgp[0]*y[16]+cgp[1]*y[17]+cgp[2]*y[18]+cgp[3]*y[19]
                                     + cgp[4]*y[20]+cgp[5]*y[21]+cgp[6]*y[22]+cgp[7]*y[23]
                                     + cgp[8]*y[24]; break;
                        }
                        s_cgy[eloc][o*8 + i] = s * nrm;
                    }
                }
                __asm__ volatile("" ::: "memory");   // cgY visible (intra-wave exchange)

                // tmp[v=l, o] -> B-frag bf16 [e][n=ob+o][v]; zero only vacated slots
                unsigned short* tb = &s_tB[pb*PBS + eloc*ES + l];
                if (p == 3 || p == 4)        { tb[0] = 0; }
                else if (p == 10 || p == 11) { tb[WS] = 0; tb[2*WS] = 0; tb[3*WS] = 0; }
                if (ii == 0) {
                    for (int o = 0; o < dO; ++o) {
                        const float c0 = s_cgy[eloc][o*8];
                        tb[(ob + o)*WS] = to_bf16(fv[0]*c0);
                    }
                } else if (ii == 1) {
                    for (int o = 0; o < dO; ++o) {
                        const float4 c4 = *reinterpret_cast<const float4*>(&s_cgy[eloc][o*8]);
                        tb[(ob + o)*WS] = to_bf16(fv[1]*c4.x + fv[2]*c4.y + fv[3]*c4.z);
                    }
                } else {
                    for (int o = 0; o < dO; ++o) {
                        const float4 c4 = *reinterpret_cast<const float4*>(&s_cgy[eloc][o*8]);
                        const float c4e = s_cgy[eloc][o*8 + 4];
                        tb[(ob + o)*WS] = to_bf16(fv[4]*c4.x + fv[5]*c4.y + fv[6]*c4.z
                                                + fv[7]*c4.w + fv[8]*c4e);
                    }
                }
                __asm__ volatile("" ::: "memory");   // WAR on s_cgy before next pb
            } else {
                // p == 19 pad: zero our W slots (A==0 kills stale tb of this K-half)
                const short4 z = {0, 0, 0, 0};
                #pragma unroll
                for (int tt = 0; tt < 4; ++tt)
                    *reinterpret_cast<short4*>(
                        &s_Wa[pb*PBS + n16*ES + (4*wv + tt)*WS + q*4]) = z;
            }
        }
        __syncthreads();   // W (cross-wave w-tiles) staged for this K-block

        // MFMA-2 K-step: msg_e(16w x 16n) += Wstack_e(16x32) @ tmpstack_e(32x16)
        // A[m=w=n16][k=q*8+j]; k -> (kh=q>>1, v=(q&1)*8+j). B symmetric with n=o.
        {
            const int kh = q >> 1;
            const int vh = (q & 1) * 8;
            #pragma unroll
            for (int ee = 0; ee < 4; ++ee) {
                const int eK = 4*wv + ee;
                const bf16x8 Af = *reinterpret_cast<const bf16x8*>(
                                      &s_Wa[kh*PBS + eK*ES + n16*WS + vh]);
                const bf16x8 Bf = *reinterpret_cast<const bf16x8*>(
                                      &s_tB[kh*PBS + eK*ES + n16*WS + vh]);
                D[ee] = __builtin_amdgcn_mfma_f32_16x16x32_bf16(Af, Bf, D[ee], 0, 0, 0);
            }
        }
        __syncthreads();   // WAR: next K-block rewrites s_Wa
    }

    // epilogue: D[row=w=q*4+r, col=oflat=n16] -> msg[e][oflat*16 + w], float4 stores
    if (n16 < 9) {
        #pragma unroll
        for (int ee = 0; ee < 4; ++ee) {
            const int eg = blockIdx.x * EPB + 4*wv + ee;
            if (eg < nE) {
                float* mp = msg + (size_t)eg * 144 + n16*16 + q*4;
                float4 v4; v4.x = D[ee][0]; v4.y = D[ee][1]; v4.z = D[ee][2]; v4.w = D[ee][3];
                *reinterpret_cast<float4*>(mp) = v4;
            }
        }
    }
}

// ---------------- Phase B: node gather-reduce (no atomics) ----------------
__global__ __launch_bounds__(BLK)
void se3_gather(const float* __restrict__ msg, const int* __restrict__ off,
                const int* __restrict__ eidx, const float* __restrict__ Nn,
                float* __restrict__ Out, const int nN)
{
    const int l = threadIdx.x & 15;
    const int g = threadIdx.x >> 4;
    const int n = blockIdx.x * 16 + g;
    if (n >= nN) return;

    const int i0 = off[n], i1 = off[n + 1];
    float s[9];
    #pragma unroll
    for (int j = 0; j < 9; ++j) s[j] = 0.f;

    for (int idx = i0; idx < i1; ++idx) {
        const int eid = eidx[idx];
        const float* m = msg + (size_t)eid * 144 + l;
        #pragma unroll
        for (int j = 0; j < 9; ++j) s[j] += m[j * 16];
    }

    const float nn = Nn[n];
    float* orow = Out + (size_t)n * 144;
    orow[l] = s[0] * nn;
    #pragma unroll
    for (int o = 0; o < 3; ++o) orow[16 + l*3 + o] = s[1+o] * nn;
    #pragma unroll
    for (int o = 0; o < 5; ++o) orow[64 + l*5 + o] = s[4+o] * nn;
}

// ---------------- CSR build (by destination) ----------------
__global__ void k_count(const int* __restrict__ Ma, int* __restrict__ cur, int E) {
    int e = blockIdx.x * blockDim.x + threadIdx.x;
    if (e < E) atomicAdd(&cur[Ma[e]], 1);
}

__global__ void k_scan(int* __restrict__ cur, int* __restrict__ off, int N) {
    __shared__ int part[BLK];
    const int t = threadIdx.x;
    const int K = (N + BLK - 1) / BLK;
    const int i0 = t * K, i1 = min(i0 + K, N);
    int s = 0;
    for (int i = i0; i < i1; ++i) s += cur[i];
    part[t] = s;
    __syncthreads();
    if (t == 0) {
        int a = 0;
        for (int j = 0; j < BLK; ++j) { int v = part[j]; part[j] = a; a += v; }
        off[N] = a;
    }
    __syncthreads();
    int a = part[t];
    for (int i = i0; i < i1; ++i) {
        int v = cur[i];
        off[i] = a;
        cur[i] = a;       // reuse as scatter cursor
        a += v;
    }
}

__global__ void k_scatter(const int* __restrict__ Ma, int* __restrict__ cur,
                          int* __restrict__ eidx, int E) {
    int e = blockIdx.x * blockDim.x + threadIdx.x;
    if (e < E) {
        int pos = atomicAdd(&cur[Ma[e]], 1);
        eidx[pos] = e;
    }
}

extern "C" void kernel_launch(void* const* d_in, const int* in_sizes, int n_in,
                              void* d_out, int out_size, void* d_ws, size_t ws_size,
                              hipStream_t stream) {
    const float* F   = (const float*)d_in[0];
    const float* R   = (const float*)d_in[1];
    const float* Ys  = (const float*)d_in[2];
    const float* Rad = (const float*)d_in[3];
    const float* cg  = (const float*)d_in[4];
    const float* Nn  = (const float*)d_in[5];
    const int*   Ma  = (const int*)d_in[6];
    const int*   Mb  = (const int*)d_in[7];
    float* Out = (float*)d_out;

    const int nE = in_sizes[6];   // edges
    const int nN = in_sizes[5];   // nodes

    // ws layout: [cur nN][off nN+1][eidx nE][pad][msg nE*144 f32][pad][Rt NP*16*64*8 bf16]
    int* wsI  = (int*)d_ws;
    int* cur  = wsI;
    int* off  = wsI + nN;
    int* eidx = wsI + 2*nN + 1;
    size_t msgOff = ((size_t)(2*nN + 1 + nE) + 63) & ~(size_t)63;
    float* msg = (float*)d_ws + msgOff;
    size_t rtOff = ((msgOff + (size_t)nE * 144) + 63) & ~(size_t)63;
    unsigned short* Rt = (unsigned short*)((float*)d_ws + rtOff);

    hipMemsetAsync(cur, 0, (size_t)nN * sizeof(int), stream);
    k_count  <<<(nE + BLK - 1) / BLK, BLK, 0, stream>>>(Ma, cur, nE);
    k_scan   <<<1, BLK, 0, stream>>>(cur, off, nN);
    k_scatter<<<(nE + BLK - 1) / BLK, BLK, 0, stream>>>(Ma, cur, eidx, nE);
    k_rt     <<<(NP*16*64*8 + BLK - 1) / BLK, BLK, 0, stream>>>(R, Rt);

    se3_msg   <<<(nE + EPB - 1) / EPB, BLK, 0, stream>>>(F, Ys, Rad, cg, Rt, Mb, msg, nE);
    se3_gather<<<(nN + 15) / 16, BLK, 0, stream>>>(msg, off, eidx, Nn, Out, nN);
}